// Round 14
// baseline (302.009 us; speedup 1.0000x reference)
//
#include <hip/hip_runtime.h>

// Problem constants (Qwen3MoE attention prefill)
#define B_   2
#define S_   1024
#define HID_ 2048
#define H_   32
#define HK_  4
#define D_   128
#define NQKV ((H_ + 2 * HK_) * D_)   // 5120
#define TOK  (B_ * S_)               // 2048

typedef short bf16x8  __attribute__((ext_vector_type(8)));  // 8 bf16 (4 VGPRs)
typedef short short4v __attribute__((ext_vector_type(4)));
typedef float f32x4   __attribute__((ext_vector_type(4)));
typedef int   i32x4   __attribute__((ext_vector_type(4)));

__device__ inline short f2bf(float f) {
  unsigned u = __builtin_bit_cast(unsigned, f);
  u += 0x7fffu + ((u >> 16) & 1u);   // round-to-nearest-even
  return (short)(u >> 16);
}
__device__ inline float bf2f(short s) {
  return __builtin_bit_cast(float, ((unsigned)(unsigned short)s) << 16);
}

// async global->LDS, 16B per lane; LDS dest is wave-uniform base + lane*16
__device__ __forceinline__ void gld_lds16(const short* g, short* l) {
  __builtin_amdgcn_global_load_lds((__attribute__((address_space(1))) void*)g,
                                   (__attribute__((address_space(3))) void*)l, 16, 0, 0);
}

// ---------------------------------------------------------------- cast fp32 -> bf16
__global__ __launch_bounds__(256) void cast_f32_bf16(const float* __restrict__ in,
                                                     short* __restrict__ out, int n4) {
  int i = blockIdx.x * 256 + threadIdx.x;
  if (i >= n4) return;
  f32x4 v = ((const f32x4*)in)[i];
  short4v o;
  o[0] = f2bf(v[0]); o[1] = f2bf(v[1]); o[2] = f2bf(v[2]); o[3] = f2bf(v[3]);
  ((short4v*)out)[i] = o;
}

// ---------------------------------------------------------------- transpose+cast: [K][N] f32 -> [N][K] bf16
// 64x64 tiles, short4 writes (128 B contiguous per 16-lane group). LDS [64][65].
__global__ __launch_bounds__(256) void transpose_cast64(const float* __restrict__ in,
                                                        short* __restrict__ out,
                                                        int K, int N) {
  __shared__ float tile[64][65];
  const int nb = blockIdx.x * 64, kb = blockIdx.y * 64;
  const int c = threadIdx.x & 63, r0 = threadIdx.x >> 6;   // 4 rows/pass
#pragma unroll
  for (int i = 0; i < 16; i++) {
    int r = r0 + i * 4;
    tile[r][c] = in[(size_t)(kb + r) * N + nb + c];
  }
  __syncthreads();
  const int j0 = threadIdx.x >> 4;          // 0..15
  const int kq = (threadIdx.x & 15) * 4;    // 0,4,...,60
#pragma unroll
  for (int i = 0; i < 4; i++) {
    int j = j0 + i * 16;                    // out row nb+j
    short4v o;
#pragma unroll
    for (int t = 0; t < 4; t++) o[t] = f2bf(tile[kq + t][j]);
    *(short4v*)&out[(size_t)(nb + j) * K + kb + kq] = o;
  }
}

// ---------------------------------------------------------------- out-proj GEMM, 64x128 tile, K-unroll-2 (R14)
// Same lever measured +4% on gemm_qkv (R13): stage TWO 64-wide K-slabs per barrier
// pair -> drain events halved. Structurally identical kernel, so it transfers.
// Grid (N/128, M/64, 2) = 1024 blocks; LDS 48 KB (3/CU residency cap).
// Store epilogue + separate add2 pass (R9 lesson: f32 atomics cost ~+20 µs).
__global__ __launch_bounds__(256, 4) void gemm_bt64(const short* __restrict__ A,
                                                    const short* __restrict__ Bt,
                                                    float* __restrict__ C,
                                                    int M, int N, int Kfull, int klen) {
  const int tid  = threadIdx.x;
  const int m0   = blockIdx.y * 64;
  const int n0   = blockIdx.x * 128;
  const int kz0  = blockIdx.z * klen;
  const int w    = tid >> 6, lane = tid & 63;
  const int quad = lane >> 4, l16 = lane & 15;
  const int wm   = (w >> 1) * 32, wn = (w & 1) * 64;

  __shared__ short As[2][64 * 64];    // 16 KB
  __shared__ short Bs[2][128 * 64];   // 32 KB

  const f32x4 z = {0.f, 0.f, 0.f, 0.f};
  f32x4 acc[2][4];
#pragma unroll
  for (int i = 0; i < 2; i++)
#pragma unroll
    for (int j = 0; j < 4; j++) acc[i][j] = z;

  const int srow = lane >> 3;           // row within 8-row issue group
  const int lc   = (lane & 7) ^ srow;   // logical chunk this lane fetches

  for (int kk = 0; kk < klen; kk += 128) {
#pragma unroll
    for (int h2 = 0; h2 < 2; h2++) {    // two 64-wide K-slabs per barrier pair
      const int k0 = kz0 + kk + h2 * 64;
#pragma unroll
      for (int i = 0; i < 2; i++) {     // A: 64 rows, 2 groups of 8 per wave
        int rb = w * 16 + i * 8;
        gld_lds16(&A[(size_t)(m0 + rb + srow) * Kfull + k0 + lc * 8], &As[h2][rb * 64]);
      }
#pragma unroll
      for (int i = 0; i < 4; i++) {     // B: 128 rows, 4 groups of 8 per wave
        int rb = w * 32 + i * 8;
        gld_lds16(&Bt[(size_t)(n0 + rb + srow) * Kfull + k0 + lc * 8], &Bs[h2][rb * 64]);
      }
    }
    __syncthreads();
#pragma unroll
    for (int h2 = 0; h2 < 2; h2++) {
#pragma unroll
      for (int kb = 0; kb < 2; kb++) {
        const int pc = ((kb * 4 + quad) ^ (l16 & 7)) * 8;
        bf16x8 a[2], b[4];
#pragma unroll
        for (int f = 0; f < 2; f++)
          a[f] = *(const bf16x8*)&As[h2][(wm + f * 16 + l16) * 64 + pc];
#pragma unroll
        for (int f = 0; f < 4; f++)
          b[f] = *(const bf16x8*)&Bs[h2][(wn + f * 16 + l16) * 64 + pc];
#pragma unroll
        for (int fi = 0; fi < 2; fi++)
#pragma unroll
          for (int fj = 0; fj < 4; fj++)
            acc[fi][fj] = __builtin_amdgcn_mfma_f32_16x16x32_bf16(a[fi], b[fj], acc[fi][fj], 0, 0, 0);
      }
    }
    __syncthreads();
  }

  float* Cz = C + (size_t)blockIdx.z * M * N;
#pragma unroll
  for (int fi = 0; fi < 2; fi++) {
    int row0 = m0 + wm + fi * 16 + quad * 4;
#pragma unroll
    for (int fj = 0; fj < 4; fj++) {
      int col = n0 + wn + fj * 16 + l16;
#pragma unroll
      for (int r = 0; r < 4; r++)
        Cz[(size_t)(row0 + r) * N + col] = acc[fi][fj][r];
    }
  }
}

// ---------------------------------------------------------------- split-K reduce: out = a + b
__global__ __launch_bounds__(256) void add2(const float* __restrict__ a,
                                            const float* __restrict__ b,
                                            float* __restrict__ c, int n4) {
  int i = blockIdx.x * 256 + threadIdx.x;
  if (i >= n4) return;
  f32x4 va = ((const f32x4*)a)[i], vb = ((const f32x4*)b)[i];
  ((f32x4*)c)[i] = va + vb;
}

// ---------------------------------------------------------------- fused QKV GEMM, 64x128 tile, K-unroll-2 (R13 proven)
// R3/R5 structure + K unrolled by 2: stage TWO 64-wide K-slabs into paired buffers,
// ONE barrier pair per 128 of K -> drain events 32 -> 16 (measured 68.3 -> 65.3 µs).
// BN=128 = one head -> fused per-head RMSNorm + RoPE (q/k) / transposed store (v).
__global__ __launch_bounds__(256, 4) void gemm_qkv(const short* __restrict__ A,
                                                   const short* __restrict__ Bt,
                                                   const float* __restrict__ cosT,
                                                   const float* __restrict__ sinT,
                                                   const float* __restrict__ qw,
                                                   const float* __restrict__ kw,
                                                   short* __restrict__ Qb,
                                                   short* __restrict__ Kb,
                                                   short* __restrict__ Vt) {
  const int tid  = threadIdx.x;
  const int m0   = blockIdx.y * 64;
  const int n0   = blockIdx.x * 128;
  const int w    = tid >> 6, lane = tid & 63;
  const int quad = lane >> 4, l16 = lane & 15;
  const int wm   = (w >> 1) * 32, wn = (w & 1) * 64;

  __shared__ short As[2][64 * 64];    // 16 KB (epilogue: RoPE exchange scratch)
  __shared__ short Bs[2][128 * 64];   // 32 KB
  __shared__ float ss_lds[4][32];

  const f32x4 z = {0.f, 0.f, 0.f, 0.f};
  f32x4 acc[2][4];
#pragma unroll
  for (int i = 0; i < 2; i++)
#pragma unroll
    for (int j = 0; j < 4; j++) acc[i][j] = z;

  const int srow = lane >> 3;           // row within 8-row issue group
  const int lc   = (lane & 7) ^ srow;   // logical chunk this lane fetches

  for (int k0 = 0; k0 < HID_; k0 += 128) {
#pragma unroll
    for (int h2 = 0; h2 < 2; h2++) {    // two 64-wide K-slabs per barrier pair
      const int kh2 = k0 + h2 * 64;
#pragma unroll
      for (int i = 0; i < 2; i++) {     // A: 64 rows, 2 groups of 8 per wave
        int rb = w * 16 + i * 8;
        gld_lds16(&A[(size_t)(m0 + rb + srow) * HID_ + kh2 + lc * 8], &As[h2][rb * 64]);
      }
#pragma unroll
      for (int i = 0; i < 4; i++) {     // B: 128 rows, 4 groups of 8 per wave
        int rb = w * 32 + i * 8;
        gld_lds16(&Bt[(size_t)(n0 + rb + srow) * HID_ + kh2 + lc * 8], &Bs[h2][rb * 64]);
      }
    }
    __syncthreads();
#pragma unroll
    for (int h2 = 0; h2 < 2; h2++) {
#pragma unroll
      for (int kb = 0; kb < 2; kb++) {
        const int pc = ((kb * 4 + quad) ^ (l16 & 7)) * 8;
        bf16x8 a[2], b[4];
#pragma unroll
        for (int f = 0; f < 2; f++)
          a[f] = *(const bf16x8*)&As[h2][(wm + f * 16 + l16) * 64 + pc];
#pragma unroll
        for (int f = 0; f < 4; f++)
          b[f] = *(const bf16x8*)&Bs[h2][(wn + f * 16 + l16) * 64 + pc];
#pragma unroll
        for (int fi = 0; fi < 2; fi++)
#pragma unroll
          for (int fj = 0; fj < 4; fj++)
            acc[fi][fj] = __builtin_amdgcn_mfma_f32_16x16x32_bf16(a[fi], b[fj], acc[fi][fj], 0, 0, 0);
      }
    }
    __syncthreads();
  }

  // ---------------- fused epilogue ----------------
  const int hd = n0 >> 7;                 // head slot 0..39 (n-tile == one head)
  const int bb = m0 >> 10;                // batch (m-tiles never cross batch: 1024%64==0)
  const int sW = (m0 & (S_ - 1)) + wm;    // wave's seq-row base

  if (hd >= H_ + HK_) {                   // ---- V head: bf16 transposed store [d][s]
    const int khv = hd - (H_ + HK_);
    short* dstV = Vt + ((size_t)(bb * HK_ + khv) * D_) * S_;
#pragma unroll
    for (int fi = 0; fi < 2; fi++) {
      int s = sW + fi * 16 + quad * 4;
#pragma unroll
      for (int fj = 0; fj < 4; fj++) {
        int d = wn + fj * 16 + l16;
        short4v o;
#pragma unroll
        for (int r = 0; r < 4; r++) o[r] = f2bf(acc[fi][fj][r]);
        *(short4v*)&dstV[(size_t)d * S_ + s] = o;
      }
    }
    return;
  }

  // ---- Q/K head: RMSNorm (row sum-squares over D=128 = wave pair w, w^1) ----
  float ssp[2][4];
#pragma unroll
  for (int fi = 0; fi < 2; fi++)
#pragma unroll
    for (int r = 0; r < 4; r++) {
      float t = 0.f;
#pragma unroll
      for (int fj = 0; fj < 4; fj++) t += acc[fi][fj][r] * acc[fi][fj][r];
      ssp[fi][r] = t;
    }
#pragma unroll
  for (int off = 1; off < 16; off <<= 1)
#pragma unroll
    for (int fi = 0; fi < 2; fi++)
#pragma unroll
      for (int r = 0; r < 4; r++) ssp[fi][r] += __shfl_xor(ssp[fi][r], off, 64);
  if (l16 == 0)
#pragma unroll
    for (int fi = 0; fi < 2; fi++)
#pragma unroll
      for (int r = 0; r < 4; r++) ss_lds[w][fi * 16 + quad * 4 + r] = ssp[fi][r];
  __syncthreads();
  float rn[2][4];
#pragma unroll
  for (int fi = 0; fi < 2; fi++)
#pragma unroll
    for (int r = 0; r < 4; r++) {
      int row = fi * 16 + quad * 4 + r;
      rn[fi][r] = rsqrtf((ss_lds[w][row] + ss_lds[w ^ 1][row]) * (1.0f / 128.0f) + 1e-6f);
    }
  const float* wv = (hd < H_) ? qw : kw;
  float wgt[4];
#pragma unroll
  for (int fj = 0; fj < 4; fj++) wgt[fj] = wv[wn + fj * 16 + l16];

  // ---- exchange normalized y with partner wave (RoPE d<->d^64) via dead As ----
  // per wave: 2*4 frags * 4 quad * 16 lanes * 4 rows = 2048 shorts (4 KB); 4 waves = 16 KB = As
  short* exch = &As[0][0];
  short* xown = exch + w * 2048;
  short* xpar = exch + (w ^ 1) * 2048;
#pragma unroll
  for (int fi = 0; fi < 2; fi++)
#pragma unroll
    for (int fj = 0; fj < 4; fj++) {
      short4v y4;
#pragma unroll
      for (int r = 0; r < 4; r++) y4[r] = f2bf(acc[fi][fj][r] * rn[fi][r] * wgt[fj]);
      *(short4v*)&xown[(((fi * 4 + fj) * 4 + quad) * 16 + l16) * 4] = y4;
    }
  __syncthreads();

  // ---- RoPE + store bf16 (q pre-scaled by SCALE*log2e for the attn exp2 path) ----
  const float sign = (wn == 0) ? -1.0f : 1.0f;
  const float osc  = (hd < H_) ? (0.08838834764831845f * 1.4426950408889634f) : 1.0f;
  short* dstQ = (hd < H_) ? (Qb + (((size_t)bb * H_ + hd) * S_) * D_)
                          : (Kb + (((size_t)bb * HK_ + (hd - H_)) * S_) * D_);
#pragma unroll
  for (int fi = 0; fi < 2; fi++)
#pragma unroll
    for (int fj = 0; fj < 4; fj++) {
      short4v yp4 = *(const short4v*)&xpar[(((fi * 4 + fj) * 4 + quad) * 16 + l16) * 4];
      int d = wn + fj * 16 + l16;
#pragma unroll
      for (int r = 0; r < 4; r++) {
        int s = sW + fi * 16 + quad * 4 + r;
        float y  = acc[fi][fj][r] * rn[fi][r] * wgt[fj];
        float yp = bf2f(yp4[r]);
        float c  = cosT[s * D_ + d];
        float sn = sinT[s * D_ + d];
        dstQ[(size_t)s * D_ + d] = f2bf((y * c + sign * yp * sn) * osc);
      }
    }
}

// ---------------------------------------------------------------- MFMA flash attention v6: strip-paired balance (R7 proven)
// Static-max softmax (|q.k*log2e| <= 16.3 -> p = exp2(s-18); l via ones-rows in Vs).
// Each block owns TWO 64-row q-strips, qt and 15-qt -> per-block work = 17 units for
// EVERY block (balanced by construction), and each staged K/V tile + each bk LDS read
// is amortized over both strips (R8 lesson: splitting strips halves that amortization
// and regressed 33 µs — do not revisit).
__global__ __launch_bounds__(256) void attn_mfma5(const short* __restrict__ Qb,
                                                  const short* __restrict__ Kb,
                                                  const short* __restrict__ Vt,
                                                  short* __restrict__ ctx) {
  const int qt = blockIdx.x & 7;    // strip pair (qt, 15-qt)
  const int h  = blockIdx.y;
  const int b  = blockIdx.z;
  const int kh = h >> 3;            // G = 8
  const int q0a = qt * 64;          // low strip row base
  const int q0b = (15 - qt) * 64;   // high strip row base
  const int tid = threadIdx.x, w = tid >> 6, lane = tid & 63;
  const int quad = lane >> 4, l16 = lane & 15;
  const float MBIAS = 18.0f;        // static softmax max (log2 units)

  __shared__ short Ks[128 * 64];        // K tile: row = key + 64*dhalf, XOR-swizzled
  __shared__ short Vs[144 * 64];        // V^T tile: row = d (128..143 = ones), XOR-swizzled
  __shared__ short Ps[4][2][16 * 72];   // per-(wave,strip) P [qrow][key]

  for (int i = tid; i < 16 * 64; i += 256) Vs[128 * 64 + i] = (short)0x3F80;

  const short* Qh = Qb + ((size_t)b * H_ + h) * S_ * D_;
  bf16x8 aq[2][4];
#pragma unroll
  for (int kb = 0; kb < 4; kb++) {
    aq[0][kb] = *(const bf16x8*)&Qh[(size_t)(q0a + w * 16 + l16) * D_ + kb * 32 + quad * 8];
    aq[1][kb] = *(const bf16x8*)&Qh[(size_t)(q0b + w * 16 + l16) * D_ + kb * 32 + quad * 8];
  }

  const f32x4 z = {0.f, 0.f, 0.f, 0.f};
  f32x4 O[2][9];                        // nb2=8 is the l column
#pragma unroll
  for (int fi = 0; fi < 2; fi++)
#pragma unroll
    for (int n = 0; n < 9; n++) O[fi][n] = z;

  const short* Kbase = Kb + ((size_t)(b * HK_ + kh) * S_) * D_;
  const short* Vbase = Vt + ((size_t)(b * HK_ + kh) * D_) * S_;

  const int srow = lane >> 3;
  const int lc   = (lane & 7) ^ srow;

  const int nkt = 16 - qt;              // 64-key tiles needed by the high strip
  for (int kt = 0; kt < nkt; kt++) {
    const int k0 = kt * 64;
    const bool doA = (kt <= qt);        // low strip still active? (wave-uniform)
    __syncthreads();
#pragma unroll
    for (int i = 0; i < 4; i++) {
      int rb = w * 32 + i * 8;
      int rr = rb + srow;
      gld_lds16(&Kbase[(size_t)(k0 + (rr & 63)) * D_ + (rr >> 6) * 64 + lc * 8], &Ks[rb * 64]);
      gld_lds16(&Vbase[(size_t)rr * S_ + k0 + lc * 8], &Vs[rb * 64]);
    }
    __syncthreads();

    // ---- QK^T + static-max softmax + P write, nb-outer, bk shared across strips
#pragma unroll
    for (int nb = 0; nb < 4; nb++) {
      f32x4 s0 = z, s1 = z;
#pragma unroll
      for (int kb = 0; kb < 4; kb++) {
        const int c  = kb * 4 + quad;
        const int c7 = c & 7;
        const int rr = (c >> 3) * 64 + nb * 16 + l16;
        bf16x8 bk = *(const bf16x8*)&Ks[rr * 64 + (c7 ^ (l16 & 7)) * 8];
        if (doA) s0 = __builtin_amdgcn_mfma_f32_16x16x32_bf16(aq[0][kb], bk, s0, 0, 0, 0);
        s1 = __builtin_amdgcn_mfma_f32_16x16x32_bf16(aq[1][kb], bk, s1, 0, 0, 0);
      }
      const int col = k0 + nb * 16 + l16;
#pragma unroll
      for (int r = 0; r < 4; r++) {
        int rowB = q0b + w * 16 + quad * 4 + r;
        float p1 = (col > rowB) ? 0.0f : exp2f(s1[r] - MBIAS);
        Ps[w][1][(quad * 4 + r) * 72 + nb * 16 + l16] = f2bf(p1);
      }
      if (doA) {
#pragma unroll
        for (int r = 0; r < 4; r++) {
          int rowA = q0a + w * 16 + quad * 4 + r;
          float p0 = (col > rowA) ? 0.0f : exp2f(s0[r] - MBIAS);
          Ps[w][0][(quad * 4 + r) * 72 + nb * 16 + l16] = f2bf(p0);
        }
      }
    }

    // ---- PV: bv shared across strips; nb2=8 = ones -> l
#pragma unroll
    for (int kb2 = 0; kb2 < 2; kb2++) {
      bf16x8 ap1 = *(const bf16x8*)&Ps[w][1][l16 * 72 + kb2 * 32 + quad * 8];
      const int c7 = kb2 * 4 + quad;
      if (doA) {
        bf16x8 ap0 = *(const bf16x8*)&Ps[w][0][l16 * 72 + kb2 * 32 + quad * 8];
#pragma unroll
        for (int nb2 = 0; nb2 < 9; nb2++) {
          int d = nb2 * 16 + l16;
          bf16x8 bv = *(const bf16x8*)&Vs[d * 64 + (c7 ^ (d & 7)) * 8];
          O[0][nb2] = __builtin_amdgcn_mfma_f32_16x16x32_bf16(ap0, bv, O[0][nb2], 0, 0, 0);
          O[1][nb2] = __builtin_amdgcn_mfma_f32_16x16x32_bf16(ap1, bv, O[1][nb2], 0, 0, 0);
        }
      } else {
#pragma unroll
        for (int nb2 = 0; nb2 < 9; nb2++) {
          int d = nb2 * 16 + l16;
          bf16x8 bv = *(const bf16x8*)&Vs[d * 64 + (c7 ^ (d & 7)) * 8];
          O[1][nb2] = __builtin_amdgcn_mfma_f32_16x16x32_bf16(ap1, bv, O[1][nb2], 0, 0, 0);
        }
      }
    }
  }

  // ---- epilogue: O / l (fi=0 -> strip q0a, fi=1 -> strip q0b)
#pragma unroll
  for (int fi = 0; fi < 2; fi++) {
    const int qbase = fi ? q0b : q0a;
#pragma unroll
    for (int r = 0; r < 4; r++) {
      float inv = 1.0f / O[fi][8][r];
      size_t row = (size_t)(b * S_ + qbase + w * 16 + quad * 4 + r);
      short* dst = ctx + row * (H_ * D_) + h * D_;
#pragma unroll
      for (int nb2 = 0; nb2 < 8; nb2++)
        dst[nb2 * 16 + l16] = f2bf(O[fi][nb2][r] * inv);
    }
  }
}

// ---------------------------------------------------------------- launch
extern "C" void kernel_launch(void* const* d_in, const int* in_sizes, int n_in,
                              void* d_out, int out_size, void* d_ws, size_t ws_size,
                              hipStream_t stream) {
  (void)in_sizes; (void)n_in; (void)out_size; (void)ws_size;
  const float* hidden = (const float*)d_in[0];
  const float* cosT   = (const float*)d_in[1];
  const float* sinT   = (const float*)d_in[2];
  const float* wqkv   = (const float*)d_in[3];
  const float* qnw    = (const float*)d_in[4];
  const float* knw    = (const float*)d_in[5];
  const float* wo     = (const float*)d_in[6];
  float* out = (float*)d_out;

  char* ws = (char*)d_ws;
  short* Qb  = (short*)ws;                                    // 16 MB (dead after attn)
  short* Kb  = (short*)(ws + 16777216);                       //  2 MB
  short* Vt  = (short*)(ws + 16777216 + 2097152);             //  2 MB
  short* hb  = (short*)(ws + 41943040);                       //  8 MB hidden bf16
  short* wT  = (short*)(ws + 41943040 + 8388608);             // 20 MB w^T (qkv), then w_o^T
  short* ctx = (short*)(ws + 41943040 + 8388608 + 20971520);  // 16 MB ctx bf16
  float* part = (float*)ws;                                   // 32 MB split-K partials (over Qb/Kb/Vt, post-attn)

  // 1. hidden -> bf16
  cast_f32_bf16<<<4096, 256, 0, stream>>>(hidden, hb, TOK * HID_ / 4);
  // 2. w_qkv [2048][5120] -> bf16 [5120][2048]
  transpose_cast64<<<dim3(NQKV / 64, HID_ / 64), 256, 0, stream>>>(wqkv, wT, HID_, NQKV);
  // 3. fused qkv-GEMM (64x128 tile, K-unroll-2, 1280 blocks) + RMSNorm + RoPE + V-transpose
  gemm_qkv<<<dim3(NQKV / 128, TOK / 64), 256, 0, stream>>>(hb, wT, cosT, sinT, qnw, knw, Qb, Kb, Vt);
  // 4. MFMA causal GQA flash attention (strip-paired, balanced by construction) -> ctx
  attn_mfma5<<<dim3(S_ / 128, H_, B_), 256, 0, stream>>>(Qb, Kb, Vt, ctx);
  // 5. w_o [4096][2048] -> bf16 [2048][4096]
  transpose_cast64<<<dim3(HID_ / 64, (H_ * D_) / 64), 256, 0, stream>>>(wo, wT, H_ * D_, HID_);
  // 6. out = ctx @ w_o (64x128 K-unroll-2), split-K=2 -> 1024 blocks, then reduce
  gemm_bt64<<<dim3(HID_ / 128, TOK / 64, 2), 256, 0, stream>>>(ctx, wT, part, TOK, HID_, H_ * D_, (H_ * D_) / 2);
  add2<<<(TOK * HID_ / 4 + 255) / 256, 256, 0, stream>>>(part, part + (size_t)TOK * HID_, out, TOK * HID_ / 4);
}

// Round 16
// 289.312 us; speedup vs baseline: 1.0439x; 1.0439x over previous
//
#include <hip/hip_runtime.h>

// Problem constants (Qwen3MoE attention prefill)
#define B_   2
#define S_   1024
#define HID_ 2048
#define H_   32
#define HK_  4
#define D_   128
#define NQKV ((H_ + 2 * HK_) * D_)   // 5120
#define TOK  (B_ * S_)               // 2048

typedef short bf16x8  __attribute__((ext_vector_type(8)));  // 8 bf16 (4 VGPRs)
typedef short short4v __attribute__((ext_vector_type(4)));
typedef float f32x4   __attribute__((ext_vector_type(4)));
typedef int   i32x4   __attribute__((ext_vector_type(4)));

__device__ inline short f2bf(float f) {
  unsigned u = __builtin_bit_cast(unsigned, f);
  u += 0x7fffu + ((u >> 16) & 1u);   // round-to-nearest-even
  return (short)(u >> 16);
}
__device__ inline float bf2f(short s) {
  return __builtin_bit_cast(float, ((unsigned)(unsigned short)s) << 16);
}

// async global->LDS, 16B per lane; LDS dest is wave-uniform base + lane*16
__device__ __forceinline__ void gld_lds16(const short* g, short* l) {
  __builtin_amdgcn_global_load_lds((__attribute__((address_space(1))) void*)g,
                                   (__attribute__((address_space(3))) void*)l, 16, 0, 0);
}

// ---------------------------------------------------------------- cast fp32 -> bf16
__global__ __launch_bounds__(256) void cast_f32_bf16(const float* __restrict__ in,
                                                     short* __restrict__ out, int n4) {
  int i = blockIdx.x * 256 + threadIdx.x;
  if (i >= n4) return;
  f32x4 v = ((const f32x4*)in)[i];
  short4v o;
  o[0] = f2bf(v[0]); o[1] = f2bf(v[1]); o[2] = f2bf(v[2]); o[3] = f2bf(v[3]);
  ((short4v*)out)[i] = o;
}

// ---------------------------------------------------------------- transpose+cast: [K][N] f32 -> [N][K] bf16
// 64x64 tiles, short4 writes (128 B contiguous per 16-lane group). LDS [64][65].
__global__ __launch_bounds__(256) void transpose_cast64(const float* __restrict__ in,
                                                        short* __restrict__ out,
                                                        int K, int N) {
  __shared__ float tile[64][65];
  const int nb = blockIdx.x * 64, kb = blockIdx.y * 64;
  const int c = threadIdx.x & 63, r0 = threadIdx.x >> 6;   // 4 rows/pass
#pragma unroll
  for (int i = 0; i < 16; i++) {
    int r = r0 + i * 4;
    tile[r][c] = in[(size_t)(kb + r) * N + nb + c];
  }
  __syncthreads();
  const int j0 = threadIdx.x >> 4;          // 0..15
  const int kq = (threadIdx.x & 15) * 4;    // 0,4,...,60
#pragma unroll
  for (int i = 0; i < 4; i++) {
    int j = j0 + i * 16;                    // out row nb+j
    short4v o;
#pragma unroll
    for (int t = 0; t < 4; t++) o[t] = f2bf(tile[kq + t][j]);
    *(short4v*)&out[(size_t)(nb + j) * K + kb + kq] = o;
  }
}

// ---------------------------------------------------------------- out-proj GEMM, 64x128 tile, single-buffer (R5 proven)
// 1-deep LDS, 2 barriers/K-step, co-residency does the latency hiding.
// Grid (N/128, M/64, 2) = 1024 blocks = 4/CU launched. K-unroll-2 measured WORSE here
// (R14: 48 KB LDS cut residency 4->3; bt64's residency is its binding term, unlike
// qkv at 5/CU). Store epilogue + separate add2 pass (R9: f32 atomics cost ~+20 µs).
__global__ __launch_bounds__(256, 4) void gemm_bt64(const short* __restrict__ A,
                                                    const short* __restrict__ Bt,
                                                    float* __restrict__ C,
                                                    int M, int N, int Kfull, int klen) {
  const int tid  = threadIdx.x;
  const int m0   = blockIdx.y * 64;
  const int n0   = blockIdx.x * 128;
  const int kz0  = blockIdx.z * klen;
  const int w    = tid >> 6, lane = tid & 63;
  const int quad = lane >> 4, l16 = lane & 15;
  const int wm   = (w >> 1) * 32, wn = (w & 1) * 64;

  __shared__ short As[64 * 64];    // 8 KB, [row][64], chunks XOR-swizzled
  __shared__ short Bs[128 * 64];   // 16 KB

  const f32x4 z = {0.f, 0.f, 0.f, 0.f};
  f32x4 acc[2][4];
#pragma unroll
  for (int i = 0; i < 2; i++)
#pragma unroll
    for (int j = 0; j < 4; j++) acc[i][j] = z;

  const int srow = lane >> 3;           // row within 8-row issue group
  const int lc   = (lane & 7) ^ srow;   // logical chunk this lane fetches

  for (int kk = 0; kk < klen; kk += 64) {
    const int k0 = kz0 + kk;
#pragma unroll
    for (int i = 0; i < 2; i++) {       // A: 64 rows, 2 groups of 8 per wave
      int rb = w * 16 + i * 8;
      gld_lds16(&A[(size_t)(m0 + rb + srow) * Kfull + k0 + lc * 8], &As[rb * 64]);
    }
#pragma unroll
    for (int i = 0; i < 4; i++) {       // B: 128 rows, 4 groups of 8 per wave
      int rb = w * 32 + i * 8;
      gld_lds16(&Bt[(size_t)(n0 + rb + srow) * Kfull + k0 + lc * 8], &Bs[rb * 64]);
    }
    __syncthreads();
#pragma unroll
    for (int kb = 0; kb < 2; kb++) {
      const int pc = ((kb * 4 + quad) ^ (l16 & 7)) * 8;
      bf16x8 a[2], b[4];
#pragma unroll
      for (int f = 0; f < 2; f++)
        a[f] = *(const bf16x8*)&As[(wm + f * 16 + l16) * 64 + pc];
#pragma unroll
      for (int f = 0; f < 4; f++)
        b[f] = *(const bf16x8*)&Bs[(wn + f * 16 + l16) * 64 + pc];
#pragma unroll
      for (int fi = 0; fi < 2; fi++)
#pragma unroll
        for (int fj = 0; fj < 4; fj++)
          acc[fi][fj] = __builtin_amdgcn_mfma_f32_16x16x32_bf16(a[fi], b[fj], acc[fi][fj], 0, 0, 0);
    }
    __syncthreads();
  }

  float* Cz = C + (size_t)blockIdx.z * M * N;
#pragma unroll
  for (int fi = 0; fi < 2; fi++) {
    int row0 = m0 + wm + fi * 16 + quad * 4;
#pragma unroll
    for (int fj = 0; fj < 4; fj++) {
      int col = n0 + wn + fj * 16 + l16;
#pragma unroll
      for (int r = 0; r < 4; r++)
        Cz[(size_t)(row0 + r) * N + col] = acc[fi][fj][r];
    }
  }
}

// ---------------------------------------------------------------- split-K reduce: out = a + b
__global__ __launch_bounds__(256) void add2(const float* __restrict__ a,
                                            const float* __restrict__ b,
                                            float* __restrict__ c, int n4) {
  int i = blockIdx.x * 256 + threadIdx.x;
  if (i >= n4) return;
  f32x4 va = ((const f32x4*)a)[i], vb = ((const f32x4*)b)[i];
  ((f32x4*)c)[i] = va + vb;
}

// ---------------------------------------------------------------- fused QKV GEMM, 64x128 tile, K-unroll-2 (R13 proven)
// R3/R5 structure + K unrolled by 2: stage TWO 64-wide K-slabs into paired buffers,
// ONE barrier pair per 128 of K -> drain events 32 -> 16 (measured 68.3 -> 65.3 µs;
// works here at 5 blocks/CU launched, does NOT transfer to bt64 at 4/CU — R14).
// BN=128 = one head -> fused per-head RMSNorm + RoPE (q/k) / transposed store (v).
__global__ __launch_bounds__(256, 4) void gemm_qkv(const short* __restrict__ A,
                                                   const short* __restrict__ Bt,
                                                   const float* __restrict__ cosT,
                                                   const float* __restrict__ sinT,
                                                   const float* __restrict__ qw,
                                                   const float* __restrict__ kw,
                                                   short* __restrict__ Qb,
                                                   short* __restrict__ Kb,
                                                   short* __restrict__ Vt) {
  const int tid  = threadIdx.x;
  const int m0   = blockIdx.y * 64;
  const int n0   = blockIdx.x * 128;
  const int w    = tid >> 6, lane = tid & 63;
  const int quad = lane >> 4, l16 = lane & 15;
  const int wm   = (w >> 1) * 32, wn = (w & 1) * 64;

  __shared__ short As[2][64 * 64];    // 16 KB (epilogue: RoPE exchange scratch)
  __shared__ short Bs[2][128 * 64];   // 32 KB
  __shared__ float ss_lds[4][32];

  const f32x4 z = {0.f, 0.f, 0.f, 0.f};
  f32x4 acc[2][4];
#pragma unroll
  for (int i = 0; i < 2; i++)
#pragma unroll
    for (int j = 0; j < 4; j++) acc[i][j] = z;

  const int srow = lane >> 3;           // row within 8-row issue group
  const int lc   = (lane & 7) ^ srow;   // logical chunk this lane fetches

  for (int k0 = 0; k0 < HID_; k0 += 128) {
#pragma unroll
    for (int h2 = 0; h2 < 2; h2++) {    // two 64-wide K-slabs per barrier pair
      const int kh2 = k0 + h2 * 64;
#pragma unroll
      for (int i = 0; i < 2; i++) {     // A: 64 rows, 2 groups of 8 per wave
        int rb = w * 16 + i * 8;
        gld_lds16(&A[(size_t)(m0 + rb + srow) * HID_ + kh2 + lc * 8], &As[h2][rb * 64]);
      }
#pragma unroll
      for (int i = 0; i < 4; i++) {     // B: 128 rows, 4 groups of 8 per wave
        int rb = w * 32 + i * 8;
        gld_lds16(&Bt[(size_t)(n0 + rb + srow) * HID_ + kh2 + lc * 8], &Bs[h2][rb * 64]);
      }
    }
    __syncthreads();
#pragma unroll
    for (int h2 = 0; h2 < 2; h2++) {
#pragma unroll
      for (int kb = 0; kb < 2; kb++) {
        const int pc = ((kb * 4 + quad) ^ (l16 & 7)) * 8;
        bf16x8 a[2], b[4];
#pragma unroll
        for (int f = 0; f < 2; f++)
          a[f] = *(const bf16x8*)&As[h2][(wm + f * 16 + l16) * 64 + pc];
#pragma unroll
        for (int f = 0; f < 4; f++)
          b[f] = *(const bf16x8*)&Bs[h2][(wn + f * 16 + l16) * 64 + pc];
#pragma unroll
        for (int fi = 0; fi < 2; fi++)
#pragma unroll
          for (int fj = 0; fj < 4; fj++)
            acc[fi][fj] = __builtin_amdgcn_mfma_f32_16x16x32_bf16(a[fi], b[fj], acc[fi][fj], 0, 0, 0);
      }
    }
    __syncthreads();
  }

  // ---------------- fused epilogue ----------------
  const int hd = n0 >> 7;                 // head slot 0..39 (n-tile == one head)
  const int bb = m0 >> 10;                // batch (m-tiles never cross batch: 1024%64==0)
  const int sW = (m0 & (S_ - 1)) + wm;    // wave's seq-row base

  if (hd >= H_ + HK_) {                   // ---- V head: bf16 transposed store [d][s]
    const int khv = hd - (H_ + HK_);
    short* dstV = Vt + ((size_t)(bb * HK_ + khv) * D_) * S_;
#pragma unroll
    for (int fi = 0; fi < 2; fi++) {
      int s = sW + fi * 16 + quad * 4;
#pragma unroll
      for (int fj = 0; fj < 4; fj++) {
        int d = wn + fj * 16 + l16;
        short4v o;
#pragma unroll
        for (int r = 0; r < 4; r++) o[r] = f2bf(acc[fi][fj][r]);
        *(short4v*)&dstV[(size_t)d * S_ + s] = o;
      }
    }
    return;
  }

  // ---- Q/K head: RMSNorm (row sum-squares over D=128 = wave pair w, w^1) ----
  float ssp[2][4];
#pragma unroll
  for (int fi = 0; fi < 2; fi++)
#pragma unroll
    for (int r = 0; r < 4; r++) {
      float t = 0.f;
#pragma unroll
      for (int fj = 0; fj < 4; fj++) t += acc[fi][fj][r] * acc[fi][fj][r];
      ssp[fi][r] = t;
    }
#pragma unroll
  for (int off = 1; off < 16; off <<= 1)
#pragma unroll
    for (int fi = 0; fi < 2; fi++)
#pragma unroll
      for (int r = 0; r < 4; r++) ssp[fi][r] += __shfl_xor(ssp[fi][r], off, 64);
  if (l16 == 0)
#pragma unroll
    for (int fi = 0; fi < 2; fi++)
#pragma unroll
      for (int r = 0; r < 4; r++) ss_lds[w][fi * 16 + quad * 4 + r] = ssp[fi][r];
  __syncthreads();
  float rn[2][4];
#pragma unroll
  for (int fi = 0; fi < 2; fi++)
#pragma unroll
    for (int r = 0; r < 4; r++) {
      int row = fi * 16 + quad * 4 + r;
      rn[fi][r] = rsqrtf((ss_lds[w][row] + ss_lds[w ^ 1][row]) * (1.0f / 128.0f) + 1e-6f);
    }
  const float* wv = (hd < H_) ? qw : kw;
  float wgt[4];
#pragma unroll
  for (int fj = 0; fj < 4; fj++) wgt[fj] = wv[wn + fj * 16 + l16];

  // ---- exchange normalized y with partner wave (RoPE d<->d^64) via dead As ----
  // per wave: 2*4 frags * 4 quad * 16 lanes * 4 rows = 2048 shorts (4 KB); 4 waves = 16 KB = As
  short* exch = &As[0][0];
  short* xown = exch + w * 2048;
  short* xpar = exch + (w ^ 1) * 2048;
#pragma unroll
  for (int fi = 0; fi < 2; fi++)
#pragma unroll
    for (int fj = 0; fj < 4; fj++) {
      short4v y4;
#pragma unroll
      for (int r = 0; r < 4; r++) y4[r] = f2bf(acc[fi][fj][r] * rn[fi][r] * wgt[fj]);
      *(short4v*)&xown[(((fi * 4 + fj) * 4 + quad) * 16 + l16) * 4] = y4;
    }
  __syncthreads();

  // ---- RoPE + store bf16 (q pre-scaled by SCALE*log2e for the attn exp2 path) ----
  const float sign = (wn == 0) ? -1.0f : 1.0f;
  const float osc  = (hd < H_) ? (0.08838834764831845f * 1.4426950408889634f) : 1.0f;
  short* dstQ = (hd < H_) ? (Qb + (((size_t)bb * H_ + hd) * S_) * D_)
                          : (Kb + (((size_t)bb * HK_ + (hd - H_)) * S_) * D_);
#pragma unroll
  for (int fi = 0; fi < 2; fi++)
#pragma unroll
    for (int fj = 0; fj < 4; fj++) {
      short4v yp4 = *(const short4v*)&xpar[(((fi * 4 + fj) * 4 + quad) * 16 + l16) * 4];
      int d = wn + fj * 16 + l16;
#pragma unroll
      for (int r = 0; r < 4; r++) {
        int s = sW + fi * 16 + quad * 4 + r;
        float y  = acc[fi][fj][r] * rn[fi][r] * wgt[fj];
        float yp = bf2f(yp4[r]);
        float c  = cosT[s * D_ + d];
        float sn = sinT[s * D_ + d];
        dstQ[(size_t)s * D_ + d] = f2bf((y * c + sign * yp * sn) * osc);
      }
    }
}

// ---------------------------------------------------------------- MFMA flash attention v6: strip-paired balance (R7 proven)
// Static-max softmax (|q.k*log2e| <= 16.3 -> p = exp2(s-18); l via ones-rows in Vs).
// Each block owns TWO 64-row q-strips, qt and 15-qt -> per-block work = 17 units for
// EVERY block (balanced by construction), and each staged K/V tile + each bk LDS read
// is amortized over both strips (R8 lesson: splitting strips halves that amortization
// and regressed 33 µs — do not revisit).
__global__ __launch_bounds__(256) void attn_mfma5(const short* __restrict__ Qb,
                                                  const short* __restrict__ Kb,
                                                  const short* __restrict__ Vt,
                                                  short* __restrict__ ctx) {
  const int qt = blockIdx.x & 7;    // strip pair (qt, 15-qt)
  const int h  = blockIdx.y;
  const int b  = blockIdx.z;
  const int kh = h >> 3;            // G = 8
  const int q0a = qt * 64;          // low strip row base
  const int q0b = (15 - qt) * 64;   // high strip row base
  const int tid = threadIdx.x, w = tid >> 6, lane = tid & 63;
  const int quad = lane >> 4, l16 = lane & 15;
  const float MBIAS = 18.0f;        // static softmax max (log2 units)

  __shared__ short Ks[128 * 64];        // K tile: row = key + 64*dhalf, XOR-swizzled
  __shared__ short Vs[144 * 64];        // V^T tile: row = d (128..143 = ones), XOR-swizzled
  __shared__ short Ps[4][2][16 * 72];   // per-(wave,strip) P [qrow][key]

  for (int i = tid; i < 16 * 64; i += 256) Vs[128 * 64 + i] = (short)0x3F80;

  const short* Qh = Qb + ((size_t)b * H_ + h) * S_ * D_;
  bf16x8 aq[2][4];
#pragma unroll
  for (int kb = 0; kb < 4; kb++) {
    aq[0][kb] = *(const bf16x8*)&Qh[(size_t)(q0a + w * 16 + l16) * D_ + kb * 32 + quad * 8];
    aq[1][kb] = *(const bf16x8*)&Qh[(size_t)(q0b + w * 16 + l16) * D_ + kb * 32 + quad * 8];
  }

  const f32x4 z = {0.f, 0.f, 0.f, 0.f};
  f32x4 O[2][9];                        // nb2=8 is the l column
#pragma unroll
  for (int fi = 0; fi < 2; fi++)
#pragma unroll
    for (int n = 0; n < 9; n++) O[fi][n] = z;

  const short* Kbase = Kb + ((size_t)(b * HK_ + kh) * S_) * D_;
  const short* Vbase = Vt + ((size_t)(b * HK_ + kh) * D_) * S_;

  const int srow = lane >> 3;
  const int lc   = (lane & 7) ^ srow;

  const int nkt = 16 - qt;              // 64-key tiles needed by the high strip
  for (int kt = 0; kt < nkt; kt++) {
    const int k0 = kt * 64;
    const bool doA = (kt <= qt);        // low strip still active? (wave-uniform)
    __syncthreads();
#pragma unroll
    for (int i = 0; i < 4; i++) {
      int rb = w * 32 + i * 8;
      int rr = rb + srow;
      gld_lds16(&Kbase[(size_t)(k0 + (rr & 63)) * D_ + (rr >> 6) * 64 + lc * 8], &Ks[rb * 64]);
      gld_lds16(&Vbase[(size_t)rr * S_ + k0 + lc * 8], &Vs[rb * 64]);
    }
    __syncthreads();

    // ---- QK^T + static-max softmax + P write, nb-outer, bk shared across strips
#pragma unroll
    for (int nb = 0; nb < 4; nb++) {
      f32x4 s0 = z, s1 = z;
#pragma unroll
      for (int kb = 0; kb < 4; kb++) {
        const int c  = kb * 4 + quad;
        const int c7 = c & 7;
        const int rr = (c >> 3) * 64 + nb * 16 + l16;
        bf16x8 bk = *(const bf16x8*)&Ks[rr * 64 + (c7 ^ (l16 & 7)) * 8];
        if (doA) s0 = __builtin_amdgcn_mfma_f32_16x16x32_bf16(aq[0][kb], bk, s0, 0, 0, 0);
        s1 = __builtin_amdgcn_mfma_f32_16x16x32_bf16(aq[1][kb], bk, s1, 0, 0, 0);
      }
      const int col = k0 + nb * 16 + l16;
#pragma unroll
      for (int r = 0; r < 4; r++) {
        int rowB = q0b + w * 16 + quad * 4 + r;
        float p1 = (col > rowB) ? 0.0f : exp2f(s1[r] - MBIAS);
        Ps[w][1][(quad * 4 + r) * 72 + nb * 16 + l16] = f2bf(p1);
      }
      if (doA) {
#pragma unroll
        for (int r = 0; r < 4; r++) {
          int rowA = q0a + w * 16 + quad * 4 + r;
          float p0 = (col > rowA) ? 0.0f : exp2f(s0[r] - MBIAS);
          Ps[w][0][(quad * 4 + r) * 72 + nb * 16 + l16] = f2bf(p0);
        }
      }
    }

    // ---- PV: bv shared across strips; nb2=8 = ones -> l
#pragma unroll
    for (int kb2 = 0; kb2 < 2; kb2++) {
      bf16x8 ap1 = *(const bf16x8*)&Ps[w][1][l16 * 72 + kb2 * 32 + quad * 8];
      const int c7 = kb2 * 4 + quad;
      if (doA) {
        bf16x8 ap0 = *(const bf16x8*)&Ps[w][0][l16 * 72 + kb2 * 32 + quad * 8];
#pragma unroll
        for (int nb2 = 0; nb2 < 9; nb2++) {
          int d = nb2 * 16 + l16;
          bf16x8 bv = *(const bf16x8*)&Vs[d * 64 + (c7 ^ (d & 7)) * 8];
          O[0][nb2] = __builtin_amdgcn_mfma_f32_16x16x32_bf16(ap0, bv, O[0][nb2], 0, 0, 0);
          O[1][nb2] = __builtin_amdgcn_mfma_f32_16x16x32_bf16(ap1, bv, O[1][nb2], 0, 0, 0);
        }
      } else {
#pragma unroll
        for (int nb2 = 0; nb2 < 9; nb2++) {
          int d = nb2 * 16 + l16;
          bf16x8 bv = *(const bf16x8*)&Vs[d * 64 + (c7 ^ (d & 7)) * 8];
          O[1][nb2] = __builtin_amdgcn_mfma_f32_16x16x32_bf16(ap1, bv, O[1][nb2], 0, 0, 0);
        }
      }
    }
  }

  // ---- epilogue: O / l (fi=0 -> strip q0a, fi=1 -> strip q0b)
#pragma unroll
  for (int fi = 0; fi < 2; fi++) {
    const int qbase = fi ? q0b : q0a;
#pragma unroll
    for (int r = 0; r < 4; r++) {
      float inv = 1.0f / O[fi][8][r];
      size_t row = (size_t)(b * S_ + qbase + w * 16 + quad * 4 + r);
      short* dst = ctx + row * (H_ * D_) + h * D_;
#pragma unroll
      for (int nb2 = 0; nb2 < 8; nb2++)
        dst[nb2 * 16 + l16] = f2bf(O[fi][nb2][r] * inv);
    }
  }
}

// ---------------------------------------------------------------- launch
extern "C" void kernel_launch(void* const* d_in, const int* in_sizes, int n_in,
                              void* d_out, int out_size, void* d_ws, size_t ws_size,
                              hipStream_t stream) {
  (void)in_sizes; (void)n_in; (void)out_size; (void)ws_size;
  const float* hidden = (const float*)d_in[0];
  const float* cosT   = (const float*)d_in[1];
  const float* sinT   = (const float*)d_in[2];
  const float* wqkv   = (const float*)d_in[3];
  const float* qnw    = (const float*)d_in[4];
  const float* knw    = (const float*)d_in[5];
  const float* wo     = (const float*)d_in[6];
  float* out = (float*)d_out;

  char* ws = (char*)d_ws;
  short* Qb  = (short*)ws;                                    // 16 MB (dead after attn)
  short* Kb  = (short*)(ws + 16777216);                       //  2 MB
  short* Vt  = (short*)(ws + 16777216 + 2097152);             //  2 MB
  short* hb  = (short*)(ws + 41943040);                       //  8 MB hidden bf16
  short* wT  = (short*)(ws + 41943040 + 8388608);             // 20 MB w^T (qkv), then w_o^T
  short* ctx = (short*)(ws + 41943040 + 8388608 + 20971520);  // 16 MB ctx bf16
  float* part = (float*)ws;                                   // 32 MB split-K partials (over Qb/Kb/Vt, post-attn)

  // 1. hidden -> bf16
  cast_f32_bf16<<<4096, 256, 0, stream>>>(hidden, hb, TOK * HID_ / 4);
  // 2. w_qkv [2048][5120] -> bf16 [5120][2048]
  transpose_cast64<<<dim3(NQKV / 64, HID_ / 64), 256, 0, stream>>>(wqkv, wT, HID_, NQKV);
  // 3. fused qkv-GEMM (64x128 tile, K-unroll-2, 1280 blocks) + RMSNorm + RoPE + V-transpose
  gemm_qkv<<<dim3(NQKV / 128, TOK / 64), 256, 0, stream>>>(hb, wT, cosT, sinT, qnw, knw, Qb, Kb, Vt);
  // 4. MFMA causal GQA flash attention (strip-paired, balanced by construction) -> ctx
  attn_mfma5<<<dim3(S_ / 128, H_, B_), 256, 0, stream>>>(Qb, Kb, Vt, ctx);
  // 5. w_o [4096][2048] -> bf16 [2048][4096]
  transpose_cast64<<<dim3(HID_ / 64, (H_ * D_) / 64), 256, 0, stream>>>(wo, wT, H_ * D_, HID_);
  // 6. out = ctx @ w_o (64x128 single-buffer), split-K=2 -> 1024 blocks = 4/CU, then reduce
  gemm_bt64<<<dim3(HID_ / 128, TOK / 64, 2), 256, 0, stream>>>(ctx, wT, part, TOK, HID_, H_ * D_, (H_ * D_) / 2);
  add2<<<(TOK * HID_ / 4 + 255) / 256, 256, 0, stream>>>(part, part + (size_t)TOK * HID_, out, TOK * HID_ / 4);
}